// Round 19
// baseline (13311.234 us; speedup 1.0000x reference)
//
#include <hip/hip_runtime.h>

#define NROWS 65536
#define DD 256
#define KK 1024
#define NCB 8
#define QN 16777216
#define IDXN 524288
#define MARGIN 4e-3f
#define ROWS 64

typedef __attribute__((ext_vector_type(8))) short bf16x8;
typedef __attribute__((ext_vector_type(4))) float f32x4;
typedef unsigned long long u64;

__device__ __forceinline__ float fp32_barrier(float x) {
    asm volatile("" : "+v"(x));
    return x;
}

__device__ __forceinline__ unsigned short f2bf(float x) {   // RNE fp32->bf16
    union { float f; unsigned u; } v; v.f = x;
    return (unsigned short)((v.u + 0x7fffu + ((v.u >> 16) & 1u)) >> 16);
}

__device__ __forceinline__ u64 enc_sc(float sc, int k) {
    unsigned u = __float_as_uint(sc);
    u = ((int)u < 0) ? ~u : (u | 0x80000000u);
    return ((u64)u << 32) | (unsigned)k;
}

__device__ __forceinline__ float dec_sc(u64 e) {
    unsigned u = (unsigned)(e >> 32);
    u = (u & 0x80000000u) ? (u & 0x7fffffffu) : ~u;
    return __uint_as_float(u);
}

typedef const __attribute__((address_space(1))) void* gas_ptr;
typedef __attribute__((address_space(3))) void* las_ptr;
__device__ __forceinline__ void gll16(const float* g, float* l) {
    __builtin_amdgcn_global_load_lds((gas_ptr)g, (las_ptr)l, 16, 0, 0);
}

// ---- numpy pairwise ||w||^2 per codeword (bitwise np.sum semantics) ----
__global__ void wss_kernel(const float* __restrict__ cb, float* __restrict__ wss) {
    const int g = blockIdx.x * blockDim.x + threadIdx.x;
    if (g >= NCB * KK) return;
    const float* w = cb + (size_t)g * DD;
    float res0 = 0.f, res1 = 0.f;
    #pragma unroll
    for (int half = 0; half < 2; ++half) {
        const float* p = w + half * 128;
        float acc[8];
        #pragma unroll
        for (int j = 0; j < 8; ++j) acc[j] = fp32_barrier(p[j] * p[j]);
        #pragma unroll
        for (int i = 8; i < 128; i += 8)
            #pragma unroll
            for (int j = 0; j < 8; ++j) acc[j] += fp32_barrier(p[i + j] * p[i + j]);
        const float t = ((acc[0] + acc[1]) + (acc[2] + acc[3])) +
                        ((acc[4] + acc[5]) + (acc[6] + acc[7]));
        if (half == 0) res0 = t; else res1 = t;
    }
    wss[g] = res0 + res1;
}

// ---- codebooks -> bf16, t-major chunk layout (conflict-free B reads) ----
__global__ void wbf_kernel(const float* __restrict__ cb, uint4* __restrict__ Wbf) {
    const int g = blockIdx.x * 256 + threadIdx.x;     // 262144 granules
    const int klocal = g & 63;
    const int kgt = (g >> 6) & 31;
    const int kg = kgt & 3;
    const int t  = kgt >> 2;
    const int ch = (g >> 11) & 15;
    const int c  = g >> 15;
    const float* src = cb + (size_t)(c * 1024 + ch * 64 + klocal) * DD + t * 32 + kg * 8;
    const float4 v0 = *(const float4*)(src);
    const float4 v1 = *(const float4*)(src + 4);
    uint4 o;
    o.x = (unsigned)f2bf(v0.x) | ((unsigned)f2bf(v0.y) << 16);
    o.y = (unsigned)f2bf(v0.z) | ((unsigned)f2bf(v0.w) << 16);
    o.z = (unsigned)f2bf(v1.x) | ((unsigned)f2bf(v1.y) << 16);
    o.w = (unsigned)f2bf(v1.z) | ((unsigned)f2bf(v1.w) << 16);
    Wbf[g] = o;
}

// ---- runtime MFMA A/B-layout self-verification ----
__global__ void probe_kernel(float* __restrict__ flagp) {
    const int l = threadIdx.x;
    const int m = l & 15, kb = (l >> 4) * 8;
    bf16x8 a1, a2, b1, b2;
    #pragma unroll
    for (int e = 0; e < 8; ++e) {
        a1[e] = (short)f2bf((float)m);
        a2[e] = (short)f2bf((float)(kb + e));
        b1[e] = (short)f2bf((kb + e == 5) ? 1.f : 0.f);
        b2[e] = (short)f2bf((kb + e == 5 && m == 3) ? 1.f : 0.f);
    }
    f32x4 z = {0.f, 0.f, 0.f, 0.f};
    f32x4 d1 = __builtin_amdgcn_mfma_f32_16x16x32_bf16(a1, b1, z, 0, 0, 0);
    f32x4 d2 = __builtin_amdgcn_mfma_f32_16x16x32_bf16(a2, b2, z, 0, 0, 0);
    bool ok = true;
    const int col = l & 15, rbase = (l >> 4) * 4;
    #pragma unroll
    for (int reg = 0; reg < 4; ++reg) {
        ok = ok && (d1[reg] == (float)(rbase + reg));
        ok = ok && (d2[reg] == ((col == 3) ? 5.f : 0.f));
    }
    const int good = __all(ok ? 1 : 0);
    if (l == 0) *flagp = good ? 3.0f : 1.0f;
}

// ---- fused RVQ: all 8 steps + quantized epilogue in one kernel ----
// Per step: SINGLE-pass MFMA scoring; each lane tracks top-2 (encoded u64,
// pure VALU) over its fixed 32-k subset per row-reg. Containment: if no lane
// of a row has best2 <= th (= rowmin + MARGIN, MARGIN >> 2*bf16 error), the
// true fp32 argmin (and all exact ties) is some lane's best1 <= th; those
// rows rescore candidates with the exact fp32 chain (bitwise reference
// semantics). Rows failing the test (or cnt 0/>8) take an exact full scan.
__launch_bounds__(512, 1)
__global__ void step_all_kernel(const float* __restrict__ z, const float* __restrict__ cb,
                                const unsigned short* __restrict__ Wbf,
                                float* __restrict__ out_idx, const float* __restrict__ wss,
                                double* __restrict__ loss, const float* __restrict__ flagp,
                                float* __restrict__ outq)
{
    __shared__ float r_s[ROWS][260];            // 66.6 KB fp32 residual (persists)
    __shared__ __align__(16) char pool[65536];  // union: rb (33.8K) / W dbuf (2x32K)
    __shared__ float wss_s[KK];
    __shared__ float rss_s[ROWS];
    __shared__ int cand[ROWS][8];
    __shared__ u64 encl[ROWS][8];
    __shared__ int cnt[ROWS];
    __shared__ int bad2[ROWS];
    __shared__ int ovfq[ROWS];
    __shared__ int novf;
    __shared__ int hist_s[ROWS][NCB];
    __shared__ double lred[8];
    __shared__ u64 warena[8];

    const int tid = threadIdx.x;
    const int lane = tid & 63;
    const int wv = tid >> 6;
    const int row0 = blockIdx.x * ROWS;
    const int row = tid >> 3;                  // staging mapping: 8 thr/row
    const int d0 = (tid & 7) * 32;

    // ---- initial stage: z -> r_s ----
    {
        const float* zr = z + (size_t)(row0 + row) * DD + d0;
        #pragma unroll
        for (int q = 0; q < 8; ++q)
            *(float4*)&r_s[row][d0 + q * 4] = *(const float4*)(zr + q * 4);
    }
    const int flag = (int)*flagp;              // uniform

    unsigned short (*rb)[264] = (unsigned short(*)[264])pool;

    #pragma unroll 1
    for (int c = 0; c < NCB; ++c) {
        const size_t cK = (size_t)c * KK;
        if (tid < ROWS) { cnt[tid] = 0; bad2[tid] = 0; }
        if (tid == 0) novf = 0;
        __syncthreads();   // prior-step update done; resets ordered

        // ---- rb (bf16) from r_s (own cells) ----
        {
            unsigned* rbrow = (unsigned*)&rb[row][0];
            #pragma unroll
            for (int j = 0; j < 16; ++j) {
                const float a = r_s[row][d0 + 2 * j];
                const float b = r_s[row][d0 + 2 * j + 1];
                rbrow[d0 / 2 + j] = (unsigned)f2bf(a) | ((unsigned)f2bf(b) << 16);
            }
        }
        // ---- rss: numpy pairwise (pw128 + pw128) ----
        if (tid < ROWS) {
            float res[2];
            #pragma unroll
            for (int half = 0; half < 2; ++half) {
                const int base = half * 128;
                float acc[8];
                #pragma unroll
                for (int j = 0; j < 8; ++j) {
                    const float x = r_s[tid][base + j];
                    acc[j] = fp32_barrier(x * x);
                }
                #pragma unroll
                for (int i = 8; i < 128; i += 8)
                    #pragma unroll
                    for (int j = 0; j < 8; ++j) {
                        const float x = r_s[tid][base + i + j];
                        acc[j] += fp32_barrier(x * x);
                    }
                res[half] = ((acc[0] + acc[1]) + (acc[2] + acc[3])) +
                            ((acc[4] + acc[5]) + (acc[6] + acc[7]));
            }
            rss_s[tid] = res[0] + res[1];
        }

        if (flag == 3) {
            // ======== single-pass MFMA scoring + per-lane top-2 ========
            const int rg = wv & 3;
            const int kh = wv >> 2;
            const int mrow0 = rg * 16;
            const int colk = lane & 15, kg = lane >> 4;
            const int lanebase = kg * 512 + kh * 256 + colk * 8;

            __syncthreads();   // rb + rss_s written
            bf16x8 af[8];
            #pragma unroll
            for (int t = 0; t < 8; ++t)
                af[t] = *(const bf16x8*)&rb[mrow0 + colk][t * 32 + kg * 8];

            float rssA[4];
            u64 best1[4], best2[4];
            #pragma unroll
            for (int reg = 0; reg < 4; ++reg) {
                rssA[reg] = rss_s[mrow0 + kg * 4 + reg];
                best1[reg] = 0xFFFFFFFFFFFFFFFFULL;
                best2[reg] = 0xFFFFFFFFFFFFFFFFULL;
            }
            wss_s[tid] = wss[cK + tid];
            wss_s[tid + 512] = wss[cK + tid + 512];
            __syncthreads();   // rb readers done -> pool reusable

            unsigned short* buf0 = (unsigned short*)pool;
            unsigned short* buf1 = (unsigned short*)(pool + 32768);
            const unsigned short* WbfC = Wbf + cK * 256;

            // prologue: chunk 0 -> buf0
            {
                const float* src = (const float*)WbfC;
                #pragma unroll
                for (int q = 0; q < 4; ++q) {
                    const int f = tid + 512 * q;
                    gll16(src + f * 4, (float*)buf0 + f * 4);
                }
            }
            __syncthreads();

            #pragma unroll 1
            for (int ch = 0; ch < 16; ++ch) {
                unsigned short* cur = (ch & 1) ? buf1 : buf0;
                unsigned short* nxt = (ch & 1) ? buf0 : buf1;
                if (ch + 1 < 16) {
                    const float* src = (const float*)(WbfC + (size_t)(ch + 1) * 16384);
                    #pragma unroll
                    for (int q = 0; q < 4; ++q) {
                        const int f = tid + 512 * q;
                        gll16(src + f * 4, (float*)nxt + f * 4);
                    }
                }
                #pragma unroll
                for (int s16 = 0; s16 < 2; ++s16) {
                    f32x4 acc = {0.f, 0.f, 0.f, 0.f};
                    #pragma unroll
                    for (int t = 0; t < 8; ++t) {
                        const bf16x8 bfv = *(const bf16x8*)
                            &cur[t * 2048 + s16 * 128 + lanebase];
                        acc = __builtin_amdgcn_mfma_f32_16x16x32_bf16(af[t], bfv, acc, 0, 0, 0);
                    }
                    const int k = ch * 64 + kh * 32 + s16 * 16 + colk;
                    const float ws = wss_s[k];
                    #pragma unroll
                    for (int reg = 0; reg < 4; ++reg) {
                        const float sA = __builtin_fmaf(-2.f, acc[reg], rssA[reg]) + ws;
                        const u64 e = enc_sc(sA, k);
                        const bool lt1 = e < best1[reg];
                        const u64 m2cand = (e < best2[reg]) ? e : best2[reg];
                        best2[reg] = lt1 ? best1[reg] : m2cand;
                        best1[reg] = lt1 ? e : best1[reg];
                    }
                }
                __syncthreads();   // GLL drained + all waves done with cur
            }

            // ---- extraction: rowmin via one post-loop shfl reduce ----
            #pragma unroll
            for (int reg = 0; reg < 4; ++reg) {
                u64 rm = best1[reg];
                #pragma unroll
                for (int off = 1; off < 16; off <<= 1) {
                    const u64 o = __shfl_xor(rm, off);
                    if (o < rm) rm = o;
                }
                const float th = dec_sc(rm) + MARGIN;
                unsigned tu = __float_as_uint(th);
                tu = ((int)tu < 0) ? ~tu : (tu | 0x80000000u);
                const u64 th_enc = ((u64)tu << 32) | 0xFFFFFFFFULL;
                const int rrow = mrow0 + kg * 4 + reg;
                if (best2[reg] <= th_enc) atomicAdd(&bad2[rrow], 1);
                if (best1[reg] <= th_enc) {
                    const int ix = atomicAdd(&cnt[rrow], 1);
                    if (ix < 8) cand[rrow][ix] = (int)(best1[reg] & 0xFFFFFFFFULL);
                }
            }
            __syncthreads();

            // ---- exact fp32-chain rescore of candidates ----
            {
                const int rrow = tid >> 3, slot = tid & 7;
                const int nc = cnt[rrow];
                if (bad2[rrow] == 0 && slot < (nc > 8 ? 8 : nc)) {
                    const int k = cand[rrow][slot];
                    const float* wr = cb + (cK + k) * DD;
                    float a = 0.f;
                    for (int q = 0; q < 64; ++q) {
                        const float4 w4 = *(const float4*)(wr + q * 4);
                        a = __builtin_fmaf(r_s[rrow][q * 4 + 0], w4.x, a);
                        a = __builtin_fmaf(r_s[rrow][q * 4 + 1], w4.y, a);
                        a = __builtin_fmaf(r_s[rrow][q * 4 + 2], w4.z, a);
                        a = __builtin_fmaf(r_s[rrow][q * 4 + 3], w4.w, a);
                    }
                    const float sc = (rss_s[rrow] - 2.0f * a) + wss[cK + k];
                    encl[rrow][slot] = enc_sc(sc, k);
                }
            }
            __syncthreads();
            if (tid < ROWS) {
                const int nc = cnt[tid];
                if (nc > 8 || nc == 0 || bad2[tid] != 0) {
                    const int ix = atomicAdd(&novf, 1);
                    ovfq[ix] = tid;
                } else {
                    u64 m = 0xFFFFFFFFFFFFFFFFULL;
                    for (int j = 0; j < nc; ++j)
                        if (encl[tid][j] < m) m = encl[tid][j];
                    const int ki = (int)(m & 0xFFFFFFFFULL);
                    out_idx[(size_t)(row0 + tid) * NCB + c] = (float)ki;
                    hist_s[tid][c] = ki;
                }
            }
            __syncthreads();
            const int nqo = novf;
            for (int qi = 0; qi < nqo; ++qi) {
                const int orow = ovfq[qi];
                const float rs = rss_s[orow];
                u64 best = 0xFFFFFFFFFFFFFFFFULL;
                for (int k = tid; k < KK; k += 512) {
                    const float* wr = cb + (cK + k) * DD;
                    float a = 0.f;
                    for (int q = 0; q < 64; ++q) {
                        const float4 w4 = *(const float4*)(wr + q * 4);
                        a = __builtin_fmaf(r_s[orow][q * 4 + 0], w4.x, a);
                        a = __builtin_fmaf(r_s[orow][q * 4 + 1], w4.y, a);
                        a = __builtin_fmaf(r_s[orow][q * 4 + 2], w4.z, a);
                        a = __builtin_fmaf(r_s[orow][q * 4 + 3], w4.w, a);
                    }
                    const u64 e = enc_sc((rs - 2.0f * a) + wss[cK + k], k);
                    if (e < best) best = e;
                }
                #pragma unroll
                for (int off = 1; off < 64; off <<= 1) {
                    const u64 o = __shfl_xor(best, off);
                    if (o < best) best = o;
                }
                if (lane == 0) warena[wv] = best;
                __syncthreads();
                if (tid == 0) {
                    u64 m = warena[0];
                    #pragma unroll
                    for (int w = 1; w < 8; ++w) if (warena[w] < m) m = warena[w];
                    const int ki = (int)(m & 0xFFFFFFFFULL);
                    out_idx[(size_t)(row0 + orow) * NCB + c] = (float)ki;
                    hist_s[orow][c] = ki;
                }
                __syncthreads();
            }
        } else {
            // ======== VALU fallback ========
            __syncthreads();
            {
                const int frow = tid >> 3, band = tid & 7;
                const float frss = rss_s[frow];
                u64 fb = 0xFFFFFFFFFFFFFFFFULL;
                const float* cbc = cb + cK * DD;
                for (int k = band * 128; k < band * 128 + 128; ++k) {
                    const float* wr = cbc + (size_t)k * DD;
                    float a = 0.f;
                    for (int q = 0; q < 64; ++q) {
                        const float4 w4 = *(const float4*)(wr + q * 4);
                        a = __builtin_fmaf(r_s[frow][q * 4 + 0], w4.x, a);
                        a = __builtin_fmaf(r_s[frow][q * 4 + 1], w4.y, a);
                        a = __builtin_fmaf(r_s[frow][q * 4 + 2], w4.z, a);
                        a = __builtin_fmaf(r_s[frow][q * 4 + 3], w4.w, a);
                    }
                    const u64 e = enc_sc((frss - 2.0f * a) + wss[cK + k], k);
                    if (e < fb) fb = e;
                }
                encl[frow][band] = fb;
            }
            __syncthreads();
            if (tid < ROWS) {
                u64 m = encl[tid][0];
                #pragma unroll
                for (int j = 1; j < 8; ++j) if (encl[tid][j] < m) m = encl[tid][j];
                const int ki = (int)(m & 0xFFFFFFFFULL);
                out_idx[(size_t)(row0 + tid) * NCB + c] = (float)ki;
                hist_s[tid][c] = ki;
            }
        }
        __syncthreads();   // hist_s complete

        // ---- update residual in place + loss term c ----
        {
            const int k = hist_s[row][c];
            const float* w = cb + (cK + (size_t)k) * DD + d0;
            double ssq = 0.0;
            #pragma unroll
            for (int q = 0; q < 8; ++q) {
                const float4 wv4 = *(const float4*)(w + q * 4);
                float4 rv = *(float4*)&r_s[row][d0 + q * 4];
                rv.x -= wv4.x; rv.y -= wv4.y; rv.z -= wv4.z; rv.w -= wv4.w;
                *(float4*)&r_s[row][d0 + q * 4] = rv;
                ssq += (double)rv.x * rv.x; ssq += (double)rv.y * rv.y;
                ssq += (double)rv.z * rv.z; ssq += (double)rv.w * rv.w;
            }
            for (int off = 32; off; off >>= 1) ssq += __shfl_down(ssq, off);
            if (lane == 0) lred[wv] = ssq;
        }
        __syncthreads();
        if (tid == 0) {
            double s = 0.0;
            #pragma unroll
            for (int w = 0; w < 8; ++w) s += lred[w];
            atomicAdd(&loss[c], s);
        }
    }
    __syncthreads();

    // ---- epilogue: quantized (fp32 sequential accumulation, ref order) ----
    {
        float qa[32];
        #pragma unroll
        for (int j = 0; j < 32; ++j) qa[j] = 0.f;
        for (int j = 0; j < NCB; ++j) {
            const int k = hist_s[row][j];
            const float* w = cb + ((size_t)j * KK + k) * DD + d0;
            #pragma unroll
            for (int q = 0; q < 8; ++q) {
                const float4 wv4 = *(const float4*)(w + q * 4);
                qa[q * 4 + 0] += wv4.x; qa[q * 4 + 1] += wv4.y;
                qa[q * 4 + 2] += wv4.z; qa[q * 4 + 3] += wv4.w;
            }
        }
        float* dst = outq + (size_t)(row0 + row) * DD + d0;
        #pragma unroll
        for (int q = 0; q < 8; ++q)
            *(float4*)(dst + q * 4) =
                make_float4(qa[q * 4], qa[q * 4 + 1], qa[q * 4 + 2], qa[q * 4 + 3]);
    }
}

__global__ void loss_write_kernel(const double* __restrict__ loss,
                                  float* __restrict__ out_loss) {
    double s = 0.0;
    for (int i = 0; i < NCB; ++i) s += loss[i];
    *out_loss = (float)(s / 16777216.0);
}

extern "C" void kernel_launch(void* const* d_in, const int* in_sizes, int n_in,
                              void* d_out, int out_size, void* d_ws, size_t ws_size,
                              hipStream_t stream)
{
    const float* z  = (const float*)d_in[0];
    const float* cb = (const float*)d_in[1];
    float* outq     = (float*)d_out;
    float* out_idx  = outq + QN;
    float* out_loss = outq + QN + IDXN;

    double* loss  = (double*)d_ws;                          // 64 B (8 terms)
    float*  flagp = (float*)((char*)d_ws + 576);
    float*  wss   = (float*)((char*)d_ws + 1024);
    unsigned short* Wbf = (unsigned short*)((char*)d_ws + 65536);  // 4 MB t-major

    hipMemsetAsync(d_ws, 0, 1024, stream);
    probe_kernel<<<dim3(1), dim3(64), 0, stream>>>(flagp);
    wss_kernel<<<dim3((NCB * KK + 255) / 256), dim3(256), 0, stream>>>(cb, wss);
    wbf_kernel<<<dim3(1024), dim3(256), 0, stream>>>(cb, (uint4*)Wbf);
    step_all_kernel<<<dim3(NROWS / ROWS), dim3(512), 0, stream>>>(
        z, cb, Wbf, out_idx, wss, loss, flagp, outq);
    loss_write_kernel<<<1, 1, 0, stream>>>(loss, out_loss);
}

// Round 20
// 1830.516 us; speedup vs baseline: 7.2718x; 7.2718x over previous
//
#include <hip/hip_runtime.h>

#define NROWS 65536
#define DD 256
#define KK 1024
#define NCB 8
#define QN 16777216
#define IDXN 524288
#define MARGIN 4e-3f
#define ROWS 64
#define QCAP 1024

typedef __attribute__((ext_vector_type(8))) short bf16x8;
typedef __attribute__((ext_vector_type(4))) float f32x4;
typedef unsigned long long u64;

__device__ __forceinline__ float fp32_barrier(float x) {
    asm volatile("" : "+v"(x));
    return x;
}

__device__ __forceinline__ unsigned short f2bf(float x) {   // RNE fp32->bf16
    union { float f; unsigned u; } v; v.f = x;
    return (unsigned short)((v.u + 0x7fffu + ((v.u >> 16) & 1u)) >> 16);
}

__device__ __forceinline__ u64 enc_sc(float sc, int k) {
    unsigned u = __float_as_uint(sc);
    u = ((int)u < 0) ? ~u : (u | 0x80000000u);
    return ((u64)u << 32) | (unsigned)k;
}

__device__ __forceinline__ float dec_sc(u64 e) {
    unsigned u = (unsigned)(e >> 32);
    u = (u & 0x80000000u) ? (u & 0x7fffffffu) : ~u;
    return __uint_as_float(u);
}

typedef const __attribute__((address_space(1))) void* gas_ptr;
typedef __attribute__((address_space(3))) void* las_ptr;
__device__ __forceinline__ void gll16(const float* g, float* l) {
    __builtin_amdgcn_global_load_lds((gas_ptr)g, (las_ptr)l, 16, 0, 0);
}

// ---- numpy pairwise ||w||^2 per codeword (bitwise np.sum semantics) ----
__global__ void wss_kernel(const float* __restrict__ cb, float* __restrict__ wss) {
    const int g = blockIdx.x * blockDim.x + threadIdx.x;
    if (g >= NCB * KK) return;
    const float* w = cb + (size_t)g * DD;
    float res0 = 0.f, res1 = 0.f;
    #pragma unroll
    for (int half = 0; half < 2; ++half) {
        const float* p = w + half * 128;
        float acc[8];
        #pragma unroll
        for (int j = 0; j < 8; ++j) acc[j] = fp32_barrier(p[j] * p[j]);
        #pragma unroll
        for (int i = 8; i < 128; i += 8)
            #pragma unroll
            for (int j = 0; j < 8; ++j) acc[j] += fp32_barrier(p[i + j] * p[i + j]);
        const float t = ((acc[0] + acc[1]) + (acc[2] + acc[3])) +
                        ((acc[4] + acc[5]) + (acc[6] + acc[7]));
        if (half == 0) res0 = t; else res1 = t;
    }
    wss[g] = res0 + res1;
}

// ---- codebooks -> bf16, t-major chunk layout (conflict-free B reads) ----
__global__ void wbf_kernel(const float* __restrict__ cb, uint4* __restrict__ Wbf) {
    const int g = blockIdx.x * 256 + threadIdx.x;     // 262144 granules
    const int klocal = g & 63;
    const int kgt = (g >> 6) & 31;
    const int kg = kgt & 3;
    const int t  = kgt >> 2;
    const int ch = (g >> 11) & 15;
    const int c  = g >> 15;
    const float* src = cb + (size_t)(c * 1024 + ch * 64 + klocal) * DD + t * 32 + kg * 8;
    const float4 v0 = *(const float4*)(src);
    const float4 v1 = *(const float4*)(src + 4);
    uint4 o;
    o.x = (unsigned)f2bf(v0.x) | ((unsigned)f2bf(v0.y) << 16);
    o.y = (unsigned)f2bf(v0.z) | ((unsigned)f2bf(v0.w) << 16);
    o.z = (unsigned)f2bf(v1.x) | ((unsigned)f2bf(v1.y) << 16);
    o.w = (unsigned)f2bf(v1.z) | ((unsigned)f2bf(v1.w) << 16);
    Wbf[g] = o;
}

// ---- runtime MFMA A/B-layout self-verification ----
__global__ void probe_kernel(float* __restrict__ flagp) {
    const int l = threadIdx.x;
    const int m = l & 15, kb = (l >> 4) * 8;
    bf16x8 a1, a2, b1, b2;
    #pragma unroll
    for (int e = 0; e < 8; ++e) {
        a1[e] = (short)f2bf((float)m);
        a2[e] = (short)f2bf((float)(kb + e));
        b1[e] = (short)f2bf((kb + e == 5) ? 1.f : 0.f);
        b2[e] = (short)f2bf((kb + e == 5 && m == 3) ? 1.f : 0.f);
    }
    f32x4 z = {0.f, 0.f, 0.f, 0.f};
    f32x4 d1 = __builtin_amdgcn_mfma_f32_16x16x32_bf16(a1, b1, z, 0, 0, 0);
    f32x4 d2 = __builtin_amdgcn_mfma_f32_16x16x32_bf16(a2, b2, z, 0, 0, 0);
    bool ok = true;
    const int col = l & 15, rbase = (l >> 4) * 4;
    #pragma unroll
    for (int reg = 0; reg < 4; ++reg) {
        ok = ok && (d1[reg] == (float)(rbase + reg));
        ok = ok && (d2[reg] == ((col == 3) ? 5.f : 0.f));
    }
    const int good = __all(ok ? 1 : 0);
    if (l == 0) *flagp = good ? 3.0f : 1.0f;
}

// ---- fused RVQ: all 8 steps + quantized epilogue in one kernel ----
// Per step: SINGLE-pass MFMA scoring; per-lane top-2 (u64-encoded, pure
// VALU). Rowmin merged across both kh halves via LDS. Candidate queue:
// non-bad2 lanes push best1; bad2 lanes (best2 <= th) push their entire
// 32-k subset (the only region where a sub-threshold k can hide behind
// best1). Exact fp32-chain rescore (d ascending, single acc) of queue items
// + LDS u64 atomicMin with k in low bits => bitwise reference argmin with
// first-min ties. Queue overflow / empty rows -> exact full scan.
__launch_bounds__(512, 1)
__global__ void step_all_kernel(const float* __restrict__ z, const float* __restrict__ cb,
                                const unsigned short* __restrict__ Wbf,
                                float* __restrict__ out_idx, const float* __restrict__ wss,
                                double* __restrict__ loss, const float* __restrict__ flagp,
                                float* __restrict__ outq)
{
    __shared__ float r_s[ROWS][260];            // 66.6 KB fp32 residual (persists)
    __shared__ __align__(16) char pool[65536];  // union: rb (33.8K) / W dbuf (2x32K)
    __shared__ float wss_s[KK];
    __shared__ float rss_s[ROWS];
    __shared__ float rminp[ROWS][2];
    __shared__ float rmin_s[ROWS];
    __shared__ unsigned qbuf[QCAP];             // 4 KB candidate queue
    __shared__ u64 encmin[ROWS];
    __shared__ int rowbad[ROWS];
    __shared__ int ovfq[ROWS];
    __shared__ int novf, qn;
    __shared__ int hist_s[ROWS][NCB];
    __shared__ double lred[8];
    __shared__ u64 warena[8];

    const int tid = threadIdx.x;
    const int lane = tid & 63;
    const int wv = tid >> 6;
    const int row0 = blockIdx.x * ROWS;
    const int row = tid >> 3;                  // staging mapping: 8 thr/row
    const int d0 = (tid & 7) * 32;

    // ---- initial stage: z -> r_s ----
    {
        const float* zr = z + (size_t)(row0 + row) * DD + d0;
        #pragma unroll
        for (int q = 0; q < 8; ++q)
            *(float4*)&r_s[row][d0 + q * 4] = *(const float4*)(zr + q * 4);
    }
    const int flag = (int)*flagp;              // uniform

    unsigned short (*rb)[264] = (unsigned short(*)[264])pool;

    #pragma unroll 1
    for (int c = 0; c < NCB; ++c) {
        const size_t cK = (size_t)c * KK;
        if (tid < ROWS) { rowbad[tid] = 0; encmin[tid] = 0xFFFFFFFFFFFFFFFFULL; }
        if (tid == 0) { novf = 0; qn = 0; }
        qbuf[tid] = 0xFFFFFFFFu;
        qbuf[tid + 512] = 0xFFFFFFFFu;
        __syncthreads();   // prior-step update done; resets ordered

        // ---- rb (bf16) from r_s (own cells) ----
        {
            unsigned* rbrow = (unsigned*)&rb[row][0];
            #pragma unroll
            for (int j = 0; j < 16; ++j) {
                const float a = r_s[row][d0 + 2 * j];
                const float b = r_s[row][d0 + 2 * j + 1];
                rbrow[d0 / 2 + j] = (unsigned)f2bf(a) | ((unsigned)f2bf(b) << 16);
            }
        }
        // ---- rss: numpy pairwise (pw128 + pw128) ----
        if (tid < ROWS) {
            float res[2];
            #pragma unroll
            for (int half = 0; half < 2; ++half) {
                const int base = half * 128;
                float acc[8];
                #pragma unroll
                for (int j = 0; j < 8; ++j) {
                    const float x = r_s[tid][base + j];
                    acc[j] = fp32_barrier(x * x);
                }
                #pragma unroll
                for (int i = 8; i < 128; i += 8)
                    #pragma unroll
                    for (int j = 0; j < 8; ++j) {
                        const float x = r_s[tid][base + i + j];
                        acc[j] += fp32_barrier(x * x);
                    }
                res[half] = ((acc[0] + acc[1]) + (acc[2] + acc[3])) +
                            ((acc[4] + acc[5]) + (acc[6] + acc[7]));
            }
            rss_s[tid] = res[0] + res[1];
        }

        if (flag == 3) {
            // ======== single-pass MFMA scoring + per-lane top-2 ========
            const int rg = wv & 3;
            const int kh = wv >> 2;
            const int mrow0 = rg * 16;
            const int colk = lane & 15, kg = lane >> 4;
            const int lanebase = kg * 512 + kh * 256 + colk * 8;

            __syncthreads();   // rb + rss_s written
            bf16x8 af[8];
            #pragma unroll
            for (int t = 0; t < 8; ++t)
                af[t] = *(const bf16x8*)&rb[mrow0 + colk][t * 32 + kg * 8];

            float rssA[4];
            u64 best1[4], best2[4];
            #pragma unroll
            for (int reg = 0; reg < 4; ++reg) {
                rssA[reg] = rss_s[mrow0 + kg * 4 + reg];
                best1[reg] = 0xFFFFFFFFFFFFFFFFULL;
                best2[reg] = 0xFFFFFFFFFFFFFFFFULL;
            }
            wss_s[tid] = wss[cK + tid];
            wss_s[tid + 512] = wss[cK + tid + 512];
            __syncthreads();   // rb readers done -> pool reusable

            unsigned short* buf0 = (unsigned short*)pool;
            unsigned short* buf1 = (unsigned short*)(pool + 32768);
            const unsigned short* WbfC = Wbf + cK * 256;

            // prologue: chunk 0 -> buf0
            {
                const float* src = (const float*)WbfC;
                #pragma unroll
                for (int q = 0; q < 4; ++q) {
                    const int f = tid + 512 * q;
                    gll16(src + f * 4, (float*)buf0 + f * 4);
                }
            }
            __syncthreads();

            #pragma unroll 1
            for (int ch = 0; ch < 16; ++ch) {
                unsigned short* cur = (ch & 1) ? buf1 : buf0;
                unsigned short* nxt = (ch & 1) ? buf0 : buf1;
                if (ch + 1 < 16) {
                    const float* src = (const float*)(WbfC + (size_t)(ch + 1) * 16384);
                    #pragma unroll
                    for (int q = 0; q < 4; ++q) {
                        const int f = tid + 512 * q;
                        gll16(src + f * 4, (float*)nxt + f * 4);
                    }
                }
                #pragma unroll
                for (int s16 = 0; s16 < 2; ++s16) {
                    f32x4 acc = {0.f, 0.f, 0.f, 0.f};
                    #pragma unroll
                    for (int t = 0; t < 8; ++t) {
                        const bf16x8 bfv = *(const bf16x8*)
                            &cur[t * 2048 + s16 * 128 + lanebase];
                        acc = __builtin_amdgcn_mfma_f32_16x16x32_bf16(af[t], bfv, acc, 0, 0, 0);
                    }
                    const int k = ch * 64 + kh * 32 + s16 * 16 + colk;
                    const float ws = wss_s[k];
                    #pragma unroll
                    for (int reg = 0; reg < 4; ++reg) {
                        const float sA = __builtin_fmaf(-2.f, acc[reg], rssA[reg]) + ws;
                        const u64 e = enc_sc(sA, k);
                        const bool lt1 = e < best1[reg];
                        const u64 m2cand = (e < best2[reg]) ? e : best2[reg];
                        best2[reg] = lt1 ? best1[reg] : m2cand;
                        best1[reg] = lt1 ? e : best1[reg];
                    }
                }
                __syncthreads();   // GLL drained + all waves done with cur
            }

            // ---- rowmin: reduce over 16 colk lanes, merge kh halves ----
            #pragma unroll
            for (int reg = 0; reg < 4; ++reg) {
                u64 rm = best1[reg];
                #pragma unroll
                for (int off = 1; off < 16; off <<= 1) {
                    const u64 o = __shfl_xor(rm, off);
                    if (o < rm) rm = o;
                }
                if (colk == 0) rminp[mrow0 + kg * 4 + reg][kh] = dec_sc(rm);
            }
            __syncthreads();
            if (tid < ROWS) rmin_s[tid] = fminf(rminp[tid][0], rminp[tid][1]);
            __syncthreads();

            // ---- extraction: push best1; bad2 lanes push whole 32-k subset ----
            #pragma unroll
            for (int reg = 0; reg < 4; ++reg) {
                const int rrow = mrow0 + kg * 4 + reg;
                const float th = rmin_s[rrow] + MARGIN;
                unsigned tu = __float_as_uint(th);
                tu = ((int)tu < 0) ? ~tu : (tu | 0x80000000u);
                const u64 th_enc = ((u64)tu << 32) | 0xFFFFFFFFULL;
                if (best1[reg] <= th_enc) {
                    if (best2[reg] <= th_enc) {
                        const int base = atomicAdd(&qn, 32);
                        if (base + 32 <= QCAP) {
                            int p = base;
                            #pragma unroll
                            for (int c2 = 0; c2 < 16; ++c2)
                                #pragma unroll
                                for (int s2 = 0; s2 < 2; ++s2)
                                    qbuf[p++] = ((unsigned)rrow << 10) |
                                        (unsigned)(c2 * 64 + kh * 32 + s2 * 16 + colk);
                        } else rowbad[rrow] = 1;
                    } else {
                        const int base = atomicAdd(&qn, 1);
                        if (base < QCAP)
                            qbuf[base] = ((unsigned)rrow << 10) |
                                         (unsigned)(best1[reg] & 1023ULL);
                        else rowbad[rrow] = 1;
                    }
                }
            }
            __syncthreads();

            // ---- exact fp32-chain rescore of queue items ----
            {
                const int nq = (qn < QCAP) ? qn : QCAP;
                for (int i = tid; i < nq; i += 512) {
                    const unsigned it = qbuf[i];
                    if (it == 0xFFFFFFFFu) continue;
                    const int rrow = it >> 10, k = (int)(it & 1023u);
                    const float* wr = cb + (cK + k) * DD;
                    float a = 0.f;
                    for (int q = 0; q < 64; ++q) {
                        const float4 w4 = *(const float4*)(wr + q * 4);
                        a = __builtin_fmaf(r_s[rrow][q * 4 + 0], w4.x, a);
                        a = __builtin_fmaf(r_s[rrow][q * 4 + 1], w4.y, a);
                        a = __builtin_fmaf(r_s[rrow][q * 4 + 2], w4.z, a);
                        a = __builtin_fmaf(r_s[rrow][q * 4 + 3], w4.w, a);
                    }
                    const float sc = (rss_s[rrow] - 2.0f * a) + wss_s[k];
                    atomicMin(&encmin[rrow], enc_sc(sc, k));
                }
            }
            __syncthreads();
            if (tid < ROWS) {
                if (rowbad[tid] || encmin[tid] == 0xFFFFFFFFFFFFFFFFULL) {
                    ovfq[atomicAdd(&novf, 1)] = tid;
                } else {
                    const int ki = (int)(encmin[tid] & 0xFFFFFFFFULL);
                    out_idx[(size_t)(row0 + tid) * NCB + c] = (float)ki;
                    hist_s[tid][c] = ki;
                }
            }
            __syncthreads();
            const int nqo = novf;
            for (int qi = 0; qi < nqo; ++qi) {   // defensive: exact full scan
                const int orow = ovfq[qi];
                const float rs = rss_s[orow];
                u64 best = 0xFFFFFFFFFFFFFFFFULL;
                for (int k = tid; k < KK; k += 512) {
                    const float* wr = cb + (cK + k) * DD;
                    float a = 0.f;
                    for (int q = 0; q < 64; ++q) {
                        const float4 w4 = *(const float4*)(wr + q * 4);
                        a = __builtin_fmaf(r_s[orow][q * 4 + 0], w4.x, a);
                        a = __builtin_fmaf(r_s[orow][q * 4 + 1], w4.y, a);
                        a = __builtin_fmaf(r_s[orow][q * 4 + 2], w4.z, a);
                        a = __builtin_fmaf(r_s[orow][q * 4 + 3], w4.w, a);
                    }
                    const u64 e = enc_sc((rs - 2.0f * a) + wss[cK + k], k);
                    if (e < best) best = e;
                }
                #pragma unroll
                for (int off = 1; off < 64; off <<= 1) {
                    const u64 o = __shfl_xor(best, off);
                    if (o < best) best = o;
                }
                if (lane == 0) warena[wv] = best;
                __syncthreads();
                if (tid == 0) {
                    u64 m = warena[0];
                    #pragma unroll
                    for (int w = 1; w < 8; ++w) if (warena[w] < m) m = warena[w];
                    const int ki = (int)(m & 0xFFFFFFFFULL);
                    out_idx[(size_t)(row0 + orow) * NCB + c] = (float)ki;
                    hist_s[orow][c] = ki;
                }
                __syncthreads();
            }
        } else {
            // ======== VALU fallback (probe failed; qbuf reused as u64[512]) ====
            __syncthreads();
            u64* fb_s = (u64*)qbuf;
            {
                const int frow = tid >> 3, band = tid & 7;
                const float frss = rss_s[frow];
                u64 fb = 0xFFFFFFFFFFFFFFFFULL;
                const float* cbc = cb + cK * DD;
                for (int k = band * 128; k < band * 128 + 128; ++k) {
                    const float* wr = cbc + (size_t)k * DD;
                    float a = 0.f;
                    for (int q = 0; q < 64; ++q) {
                        const float4 w4 = *(const float4*)(wr + q * 4);
                        a = __builtin_fmaf(r_s[frow][q * 4 + 0], w4.x, a);
                        a = __builtin_fmaf(r_s[frow][q * 4 + 1], w4.y, a);
                        a = __builtin_fmaf(r_s[frow][q * 4 + 2], w4.z, a);
                        a = __builtin_fmaf(r_s[frow][q * 4 + 3], w4.w, a);
                    }
                    const u64 e = enc_sc((frss - 2.0f * a) + wss[cK + k], k);
                    if (e < fb) fb = e;
                }
                fb_s[frow * 8 + band] = fb;
            }
            __syncthreads();
            if (tid < ROWS) {
                u64 m = fb_s[tid * 8];
                #pragma unroll
                for (int j = 1; j < 8; ++j) if (fb_s[tid * 8 + j] < m) m = fb_s[tid * 8 + j];
                const int ki = (int)(m & 0xFFFFFFFFULL);
                out_idx[(size_t)(row0 + tid) * NCB + c] = (float)ki;
                hist_s[tid][c] = ki;
            }
        }
        __syncthreads();   // hist_s complete

        // ---- update residual in place + loss term c ----
        {
            const int k = hist_s[row][c];
            const float* w = cb + (cK + (size_t)k) * DD + d0;
            double ssq = 0.0;
            #pragma unroll
            for (int q = 0; q < 8; ++q) {
                const float4 wv4 = *(const float4*)(w + q * 4);
                float4 rv = *(float4*)&r_s[row][d0 + q * 4];
                rv.x -= wv4.x; rv.y -= wv4.y; rv.z -= wv4.z; rv.w -= wv4.w;
                *(float4*)&r_s[row][d0 + q * 4] = rv;
                ssq += (double)rv.x * rv.x; ssq += (double)rv.y * rv.y;
                ssq += (double)rv.z * rv.z; ssq += (double)rv.w * rv.w;
            }
            for (int off = 32; off; off >>= 1) ssq += __shfl_down(ssq, off);
            if (lane == 0) lred[wv] = ssq;
        }
        __syncthreads();
        if (tid == 0) {
            double s = 0.0;
            #pragma unroll
            for (int w = 0; w < 8; ++w) s += lred[w];
            atomicAdd(&loss[c], s);
        }
    }
    __syncthreads();

    // ---- epilogue: quantized (fp32 sequential accumulation, ref order) ----
    {
        float qa[32];
        #pragma unroll
        for (int j = 0; j < 32; ++j) qa[j] = 0.f;
        for (int j = 0; j < NCB; ++j) {
            const int k = hist_s[row][j];
            const float* w = cb + ((size_t)j * KK + k) * DD + d0;
            #pragma unroll
            for (int q = 0; q < 8; ++q) {
                const float4 wv4 = *(const float4*)(w + q * 4);
                qa[q * 4 + 0] += wv4.x; qa[q * 4 + 1] += wv4.y;
                qa[q * 4 + 2] += wv4.z; qa[q * 4 + 3] += wv4.w;
            }
        }
        float* dst = outq + (size_t)(row0 + row) * DD + d0;
        #pragma unroll
        for (int q = 0; q < 8; ++q)
            *(float4*)(dst + q * 4) =
                make_float4(qa[q * 4], qa[q * 4 + 1], qa[q * 4 + 2], qa[q * 4 + 3]);
    }
}

__global__ void loss_write_kernel(const double* __restrict__ loss,
                                  float* __restrict__ out_loss) {
    double s = 0.0;
    for (int i = 0; i < NCB; ++i) s += loss[i];
    *out_loss = (float)(s / 16777216.0);
}

extern "C" void kernel_launch(void* const* d_in, const int* in_sizes, int n_in,
                              void* d_out, int out_size, void* d_ws, size_t ws_size,
                              hipStream_t stream)
{
    const float* z  = (const float*)d_in[0];
    const float* cb = (const float*)d_in[1];
    float* outq     = (float*)d_out;
    float* out_idx  = outq + QN;
    float* out_loss = outq + QN + IDXN;

    double* loss  = (double*)d_ws;                          // 64 B (8 terms)
    float*  flagp = (float*)((char*)d_ws + 576);
    float*  wss   = (float*)((char*)d_ws + 1024);
    unsigned short* Wbf = (unsigned short*)((char*)d_ws + 65536);  // 4 MB t-major

    hipMemsetAsync(d_ws, 0, 1024, stream);
    probe_kernel<<<dim3(1), dim3(64), 0, stream>>>(flagp);
    wss_kernel<<<dim3((NCB * KK + 255) / 256), dim3(256), 0, stream>>>(cb, wss);
    wbf_kernel<<<dim3(1024), dim3(256), 0, stream>>>(cb, (uint4*)Wbf);
    step_all_kernel<<<dim3(NROWS / ROWS), dim3(512), 0, stream>>>(
        z, cb, Wbf, out_idx, wss, loss, flagp, outq);
    loss_write_kernel<<<1, 1, 0, stream>>>(loss, out_loss);
}